// Round 8
// baseline (921.698 us; speedup 1.0000x reference)
//
#include <hip/hip_runtime.h>

#define EPS_LEN   1e-20f
#define EPS_DENOM 1e-6f

#define BLKA     1024

// ---- tier 1: fine buckets, packed u32 entries, 32B face records ----
#define CBF_LOG  10
#define CBF      (1 << CBF_LOG)     // 1024 vertices per bucket
#define NBCP     2048               // padded histogram size (2 per thread)
#define CAPF     6656               // per-bucket capacity (mean 6141, +6.6 sigma)

// ---- tier 2 (round-3 proven path) ----
#define CB2_LOG  13
#define CB2      (1 << CB2_LOG)
#define MAXB2    256
#define CAP2     57344
#define FST2     6
#define QLOG     11
#define QSIZE    (1 << QLOG)

// ===========================================================================
// TIER 1 kernel A: per-face compute, 32B face-record write (2x float4),
// block-coalesced binning into fine buckets. Entry = (vloc<<22)|face (u32).
// Overflow entries -> global atomics + ovf flag.
// ===========================================================================
__global__ __launch_bounds__(BLKA)
void vg_face_bin_f8(const float* __restrict__ pos, const int* __restrict__ faces,
                    const float* __restrict__ tex, const int* __restrict__ uvf,
                    float4* __restrict__ fd4, unsigned* __restrict__ E,
                    int* __restrict__ cursors, int* __restrict__ validw,
                    int* __restrict__ ovfp,
                    float* __restrict__ nacc, float* __restrict__ tacc,
                    int F, int NBC)
{
    __shared__ int h[NBCP];        // histogram -> later gbase
    __shared__ int s0[NBCP];       // scan ping
    __shared__ int s1[NBCP];       // scan pong -> later loff
    __shared__ int lfill[NBCP];
    __shared__ unsigned       spack[3 * BLKA];
    __shared__ unsigned short sbuck[3 * BLKA];

    const int t = threadIdx.x;
    const int f = blockIdx.x * BLKA + t;

    h[t] = 0; h[t + 1024] = 0;
    lfill[t] = 0; lfill[t + 1024] = 0;
    for (int i = t; i < 3 * BLKA; i += BLKA) sbuck[i] = 0xFFFFu;
    __syncthreads();

    const bool on = (f < F);
    int i0 = 0, i1 = 0, i2 = 0;
    float nx = 0, ny = 0, nz = 0, txv = 0, tyv = 0, tzv = 0;

    if (on) {
        i0 = faces[3 * f + 0]; i1 = faces[3 * f + 1]; i2 = faces[3 * f + 2];

        const float p0x = pos[3*i0+0], p0y = pos[3*i0+1], p0z = pos[3*i0+2];
        const float p1x = pos[3*i1+0], p1y = pos[3*i1+1], p1z = pos[3*i1+2];
        const float p2x = pos[3*i2+0], p2y = pos[3*i2+1], p2z = pos[3*i2+2];

        const float e1x = p1x - p0x, e1y = p1y - p0y, e1z = p1z - p0z;
        const float e2x = p2x - p0x, e2y = p2y - p0y, e2z = p2z - p0z;

        nx = e1y * e2z - e1z * e2y;
        ny = e1z * e2x - e1x * e2z;
        nz = e1x * e2y - e1y * e2x;

        const int t0 = uvf[3 * f + 0];
        const int t1 = uvf[3 * f + 1];
        const int t2 = uvf[3 * f + 2];

        const float u0x = tex[2*t0+0], u0y = tex[2*t0+1];
        const float u1x = tex[2*t1+0], u1y = tex[2*t1+1];
        const float u2x = tex[2*t2+0], u2y = tex[2*t2+1];

        const float d1x = u1x - u0x, d1y = u1y - u0y;
        const float d2x = u2x - u0x, d2y = u2y - u0y;

        float denom = d1x * d2y - d1y * d2x;
        denom = (denom > 0.0f) ? fmaxf(denom, EPS_DENOM) : fminf(denom, -EPS_DENOM);
        const float inv = 1.0f / denom;

        txv = (e1x * d2y - e2x * d1y) * inv;
        tyv = (e1y * d2y - e2y * d1y) * inv;
        tzv = (e1z * d2y - e2z * d1y) * inv;

        fd4[2 * (size_t)f]     = make_float4(nx, ny, nz, txv);
        fd4[2 * (size_t)f + 1] = make_float4(tyv, tzv, 0.0f, 0.0f);

        atomicAdd(&h[i0 >> CBF_LOG], 1);
        atomicAdd(&h[i1 >> CBF_LOG], 1);
        atomicAdd(&h[i2 >> CBF_LOG], 1);
    }
    __syncthreads();

    // inclusive scan over NBCP=2048 with 1024 threads, ping-pong Hillis-Steele
    s0[t] = h[t]; s0[t + 1024] = h[t + 1024];
    __syncthreads();
    int* src = s0; int* dst = s1;
    for (int d = 1; d < NBCP; d <<= 1) {
        dst[t] = src[t] + ((t >= d) ? src[t - d] : 0);
        const int k = t + 1024;
        dst[k] = src[k] + ((k >= d) ? src[k - d] : 0);
        __syncthreads();
        int* tmp = src; src = dst; dst = tmp;
    }
    int* loffp  = dst;
    int* gbasep = h;
    for (int k = t; k < NBCP; k += 1024) {
        const int incl = src[k];
        const int cnt  = h[k];
        const int lo   = incl - cnt;
        int gb = -1;
        if (k < NBC && cnt > 0) {
            gb = atomicAdd(&cursors[k], cnt);
            if (gb + cnt <= CAPF) atomicMax(&validw[k], gb + cnt);
            else gb = -1;                      // whole chunk falls back
        }
        loffp[k]  = lo;
        gbasep[k] = gb;
    }
    __syncthreads();

    if (on) {
        const int vi[3] = { i0, i1, i2 };
#pragma unroll
        for (int c = 0; c < 3; ++c) {
            const int v = vi[c];
            const int b = v >> CBF_LOG;
            if (gbasep[b] >= 0) {
                const int slot = atomicAdd(&lfill[b], 1);
                const int p = loffp[b] + slot;
                spack[p] = ((unsigned)(v & (CBF - 1)) << 22) | (unsigned)f;
                sbuck[p] = (unsigned short)b;
            } else {
                atomicOr(ovfp, 1);
                atomicAdd(&nacc[3*v+0], nx);
                atomicAdd(&nacc[3*v+1], ny);
                atomicAdd(&nacc[3*v+2], nz);
                atomicAdd(&tacc[3*v+0], txv);
                atomicAdd(&tacc[3*v+1], tyv);
                atomicAdd(&tacc[3*v+2], tzv);
            }
        }
    }
    __syncthreads();

    // coalesced copy-out: consecutive i in one bucket -> consecutive slots
    for (int i = t; i < 3 * BLKA; i += BLKA) {
        const unsigned b = sbuck[i];
        if (b != 0xFFFFu) {
            const int g = gbasep[b] + (i - loffp[b]);
            E[(size_t)b * CAPF + g] = spack[i];
        }
    }
}

// ===========================================================================
// TIER 1 kernel B: one block per fine bucket (512 thr, 24KB LDS -> 4 blk/CU,
// full occupancy). Pipelined single pass: 2x float4 record loads, LDS fp
// atomics, fused finalize. Global partial read only if overflow occurred.
// ===========================================================================
__global__ __launch_bounds__(512)
void vg_gather_reduce_f8(const float4* __restrict__ fd4,
                         const unsigned* __restrict__ E,
                         const int* __restrict__ validw,
                         const int* __restrict__ ovfp,
                         float* __restrict__ nacc, float* __restrict__ tacc,
                         int V)
{
    __shared__ float accn[CBF * 3];   // 12 KB
    __shared__ float acct[CBF * 3];   // 12 KB
    const int b = blockIdx.x;
    const int t = threadIdx.x;

    for (int i = t; i < CBF * 3; i += 512) { accn[i] = 0.0f; acct[i] = 0.0f; }
    __syncthreads();

    int count = validw[b];
    if (count > CAPF) count = CAPF;
    const size_t ebase = (size_t)b * CAPF;

    // software-pipelined: prefetch next entry while current record loads fly
    int e = t;
    bool have = (e < count);
    unsigned ent = have ? E[ebase + e] : 0u;
    while (have) {
        const int e2 = e + 512;
        const bool have2 = (e2 < count);
        const unsigned ent2 = have2 ? E[ebase + e2] : 0u;

        const int fidx = (int)(ent & 0x3FFFFFu);
        const int vloc = (int)(ent >> 22);
        const float4 ra = fd4[2 * (size_t)fidx];
        const float4 rb = fd4[2 * (size_t)fidx + 1];
        float* an = &accn[vloc * 3];
        float* at = &acct[vloc * 3];
        atomicAdd(an + 0, ra.x);
        atomicAdd(an + 1, ra.y);
        atomicAdd(an + 2, ra.z);
        atomicAdd(at + 0, ra.w);
        atomicAdd(at + 1, rb.x);
        atomicAdd(at + 2, rb.y);

        e = e2; ent = ent2; have = have2;
    }
    __syncthreads();

    const int ovf = *ovfp;
    const int vbase = b << CBF_LOG;
#pragma unroll
    for (int k = 0; k < CBF; k += 512) {
        const int i = t + k;
        const int v = vbase + i;
        if (v < V) {
            float nx = accn[3*i+0];
            float ny = accn[3*i+1];
            float nz = accn[3*i+2];
            float tx = acct[3*i+0];
            float ty = acct[3*i+1];
            float tz = acct[3*i+2];
            if (ovf) {
                nx += nacc[3*v+0]; ny += nacc[3*v+1]; nz += nacc[3*v+2];
                tx += tacc[3*v+0]; ty += tacc[3*v+1]; tz += tacc[3*v+2];
            }

            const float nd = nx*nx + ny*ny + nz*nz;
            if (nd > EPS_LEN) {
                const float invn = 1.0f / sqrtf(nd);
                nx *= invn; ny *= invn; nz *= invn;
            } else {
                nx = 0.0f; ny = 0.0f; nz = 1.0f;
            }

            const float td = tx*tx + ty*ty + tz*tz;
            const float invt = 1.0f / sqrtf(fmaxf(td, EPS_LEN));
            tx *= invt; ty *= invt; tz *= invt;

            const float dp = tx*nx + ty*ny + tz*nz;
            tx -= dp * nx; ty -= dp * ny; tz -= dp * nz;

            const float td2 = tx*tx + ty*ty + tz*tz;
            const float invt2 = 1.0f / sqrtf(fmaxf(td2, EPS_LEN));
            tx *= invt2; ty *= invt2; tz *= invt2;

            nacc[3*v+0] = nx; nacc[3*v+1] = ny; nacc[3*v+2] = nz;
            tacc[3*v+0] = tx; tacc[3*v+1] = ty; tacc[3*v+2] = tz;
        }
    }
}

// ===========================================================================
// TIER 2: round-3 proven path (coarse buckets, 4-pass reduce).
// ===========================================================================
__global__ __launch_bounds__(BLKA)
void vg_face_bin3(const float* __restrict__ pos, const int* __restrict__ faces,
                  const float* __restrict__ tex, const int* __restrict__ uvf,
                  float* __restrict__ face_data,
                  unsigned* __restrict__ ef, unsigned short* __restrict__ ev,
                  int* __restrict__ cursors, int* __restrict__ validw,
                  float* __restrict__ nacc, float* __restrict__ tacc,
                  int F, int NBC)
{
    __shared__ int h[MAXB2], sc[MAXB2], loff[MAXB2], lfill[MAXB2], gbase[MAXB2];
    __shared__ unsigned       sface[3 * BLKA];
    __shared__ unsigned short svloc[3 * BLKA];
    __shared__ unsigned char  sbuck[3 * BLKA];

    const int t = threadIdx.x;
    const int f = blockIdx.x * BLKA + t;

    if (t < MAXB2) { h[t] = 0; lfill[t] = 0; }
    for (int i = t; i < 3 * BLKA; i += BLKA) sbuck[i] = 0xFF;
    __syncthreads();

    const bool on = (f < F);
    int i0 = 0, i1 = 0, i2 = 0;
    float nx = 0, ny = 0, nz = 0, txv = 0, tyv = 0, tzv = 0;

    if (on) {
        i0 = faces[3 * f + 0]; i1 = faces[3 * f + 1]; i2 = faces[3 * f + 2];

        const float p0x = pos[3*i0+0], p0y = pos[3*i0+1], p0z = pos[3*i0+2];
        const float p1x = pos[3*i1+0], p1y = pos[3*i1+1], p1z = pos[3*i1+2];
        const float p2x = pos[3*i2+0], p2y = pos[3*i2+1], p2z = pos[3*i2+2];

        const float e1x = p1x - p0x, e1y = p1y - p0y, e1z = p1z - p0z;
        const float e2x = p2x - p0x, e2y = p2y - p0y, e2z = p2z - p0z;

        nx = e1y * e2z - e1z * e2y;
        ny = e1z * e2x - e1x * e2z;
        nz = e1x * e2y - e1y * e2x;

        const int t0 = uvf[3 * f + 0];
        const int t1 = uvf[3 * f + 1];
        const int t2 = uvf[3 * f + 2];

        const float u0x = tex[2*t0+0], u0y = tex[2*t0+1];
        const float u1x = tex[2*t1+0], u1y = tex[2*t1+1];
        const float u2x = tex[2*t2+0], u2y = tex[2*t2+1];

        const float d1x = u1x - u0x, d1y = u1y - u0y;
        const float d2x = u2x - u0x, d2y = u2y - u0y;

        float denom = d1x * d2y - d1y * d2x;
        denom = (denom > 0.0f) ? fmaxf(denom, EPS_DENOM) : fminf(denom, -EPS_DENOM);
        const float inv = 1.0f / denom;

        txv = (e1x * d2y - e2x * d1y) * inv;
        tyv = (e1y * d2y - e2y * d1y) * inv;
        tzv = (e1z * d2y - e2z * d1y) * inv;

        float* fd = &face_data[(size_t)f * FST2];
        reinterpret_cast<float2*>(fd)[0] = make_float2(nx, ny);
        reinterpret_cast<float2*>(fd)[1] = make_float2(nz, txv);
        reinterpret_cast<float2*>(fd)[2] = make_float2(tyv, tzv);

        atomicAdd(&h[i0 >> CB2_LOG], 1);
        atomicAdd(&h[i1 >> CB2_LOG], 1);
        atomicAdd(&h[i2 >> CB2_LOG], 1);
    }
    __syncthreads();

    if (t < MAXB2) sc[t] = h[t];
    __syncthreads();
    for (int d = 1; d < MAXB2; d <<= 1) {
        int v2 = 0;
        if (t < MAXB2) v2 = sc[t] + ((t >= d) ? sc[t - d] : 0);
        __syncthreads();
        if (t < MAXB2) sc[t] = v2;
        __syncthreads();
    }
    if (t < MAXB2) {
        loff[t] = sc[t] - h[t];
        const int cnt = h[t];
        int gb = -1;
        if (t < NBC && cnt > 0) {
            gb = atomicAdd(&cursors[t], cnt);
            if (gb + cnt <= CAP2) atomicMax(&validw[t], gb + cnt);
            else gb = -1;
        }
        gbase[t] = gb;
    }
    __syncthreads();

    if (on) {
        const int vi[3] = { i0, i1, i2 };
#pragma unroll
        for (int c = 0; c < 3; ++c) {
            const int v = vi[c];
            const int b = v >> CB2_LOG;
            if (gbase[b] >= 0) {
                const int slot = atomicAdd(&lfill[b], 1);
                const int p = loff[b] + slot;
                sface[p] = (unsigned)f;
                svloc[p] = (unsigned short)(v & (CB2 - 1));
                sbuck[p] = (unsigned char)b;
            } else {
                atomicAdd(&nacc[3*v+0], nx);
                atomicAdd(&nacc[3*v+1], ny);
                atomicAdd(&nacc[3*v+2], nz);
                atomicAdd(&tacc[3*v+0], txv);
                atomicAdd(&tacc[3*v+1], tyv);
                atomicAdd(&tacc[3*v+2], tzv);
            }
        }
    }
    __syncthreads();

    for (int i = t; i < 3 * BLKA; i += BLKA) {
        const unsigned b = sbuck[i];
        if (b != 0xFFu) {
            const int g = gbase[b] + (i - loff[b]);
            const size_t base = (size_t)b * CAP2;
            ef[base + g] = sface[i];
            ev[base + g] = svloc[i];
        }
    }
}

__global__ __launch_bounds__(BLKA)
void vg_bucket_reduce3(const float* __restrict__ face_data,
                       const unsigned* __restrict__ ef,
                       const unsigned short* __restrict__ ev,
                       const int* __restrict__ validw,
                       float* __restrict__ nacc, float* __restrict__ tacc,
                       int V)
{
    __shared__ float acc[QSIZE * 6];   // 48 KB
    const int b = blockIdx.x;
    const int t = threadIdx.x;
    int count = validw[b];
    if (count > CAP2) count = CAP2;
    const size_t ebase = (size_t)b * CAP2;
    const int vbase = b << CB2_LOG;

    for (int q = 0; q < 4; ++q) {
        for (int i = t; i < QSIZE * 6; i += BLKA) acc[i] = 0.0f;
        __syncthreads();

        for (int e = t; e < count; e += BLKA) {
            const int vloc = (int)ev[ebase + e];
            if ((vloc >> QLOG) == q) {
                const unsigned f = ef[ebase + e];
                const float* fd = &face_data[(size_t)f * FST2];
                const float2 a0 = reinterpret_cast<const float2*>(fd)[0];
                const float2 a1 = reinterpret_cast<const float2*>(fd)[1];
                const float2 a2 = reinterpret_cast<const float2*>(fd)[2];
                float* a = &acc[(vloc & (QSIZE - 1)) * 6];
                atomicAdd(a + 0, a0.x);
                atomicAdd(a + 1, a0.y);
                atomicAdd(a + 2, a1.x);
                atomicAdd(a + 3, a1.y);
                atomicAdd(a + 4, a2.x);
                atomicAdd(a + 5, a2.y);
            }
        }
        __syncthreads();

        for (int i = t; i < QSIZE; i += BLKA) {
            const int v = vbase + (q << QLOG) + i;
            if (v < V) {
                float nx = nacc[3*v+0] + acc[i*6+0];
                float ny = nacc[3*v+1] + acc[i*6+1];
                float nz = nacc[3*v+2] + acc[i*6+2];
                float tx = tacc[3*v+0] + acc[i*6+3];
                float ty = tacc[3*v+1] + acc[i*6+4];
                float tz = tacc[3*v+2] + acc[i*6+5];

                const float nd = nx*nx + ny*ny + nz*nz;
                if (nd > EPS_LEN) {
                    const float invn = 1.0f / sqrtf(nd);
                    nx *= invn; ny *= invn; nz *= invn;
                } else {
                    nx = 0.0f; ny = 0.0f; nz = 1.0f;
                }

                const float td = tx*tx + ty*ty + tz*tz;
                const float invt = 1.0f / sqrtf(fmaxf(td, EPS_LEN));
                tx *= invt; ty *= invt; tz *= invt;

                const float dp = tx*nx + ty*ny + tz*nz;
                tx -= dp * nx; ty -= dp * ny; tz -= dp * nz;

                const float td2 = tx*tx + ty*ty + tz*tz;
                const float invt2 = 1.0f / sqrtf(fmaxf(td2, EPS_LEN));
                tx *= invt2; ty *= invt2; tz *= invt2;

                nacc[3*v+0] = nx; nacc[3*v+1] = ny; nacc[3*v+2] = nz;
                tacc[3*v+0] = tx; tacc[3*v+1] = ty; tacc[3*v+2] = tz;
            }
        }
        __syncthreads();
    }
}

// ===========================================================================
// TIER 3: global-atomic fallback.
// ===========================================================================
__global__ void vg_face_kernel(const float* __restrict__ pos,
                               const int*   __restrict__ faces,
                               const float* __restrict__ tex,
                               const int*   __restrict__ uvf,
                               float* __restrict__ nacc,
                               float* __restrict__ tacc,
                               int F) {
    int f = blockIdx.x * blockDim.x + threadIdx.x;
    if (f >= F) return;

    const int i0 = faces[3*f+0], i1 = faces[3*f+1], i2 = faces[3*f+2];

    const float p0x = pos[3*i0+0], p0y = pos[3*i0+1], p0z = pos[3*i0+2];
    const float p1x = pos[3*i1+0], p1y = pos[3*i1+1], p1z = pos[3*i1+2];
    const float p2x = pos[3*i2+0], p2y = pos[3*i2+1], p2z = pos[3*i2+2];

    const float e1x = p1x - p0x, e1y = p1y - p0y, e1z = p1z - p0z;
    const float e2x = p2x - p0x, e2y = p2y - p0y, e2z = p2z - p0z;

    const float nx = e1y*e2z - e1z*e2y;
    const float ny = e1z*e2x - e1x*e2z;
    const float nz = e1x*e2y - e1y*e2x;

    const int t0 = uvf[3*f+0], t1 = uvf[3*f+1], t2 = uvf[3*f+2];

    const float u0x = tex[2*t0+0], u0y = tex[2*t0+1];
    const float u1x = tex[2*t1+0], u1y = tex[2*t1+1];
    const float u2x = tex[2*t2+0], u2y = tex[2*t2+1];

    const float d1x = u1x - u0x, d1y = u1y - u0y;
    const float d2x = u2x - u0x, d2y = u2y - u0y;

    float denom = d1x * d2y - d1y * d2x;
    denom = (denom > 0.0f) ? fmaxf(denom, EPS_DENOM) : fminf(denom, -EPS_DENOM);
    const float inv = 1.0f / denom;

    const float tx = (e1x*d2y - e2x*d1y) * inv;
    const float ty = (e1y*d2y - e2y*d1y) * inv;
    const float tz = (e1z*d2y - e2z*d1y) * inv;

    atomicAdd(&nacc[3*i0+0], nx); atomicAdd(&nacc[3*i0+1], ny); atomicAdd(&nacc[3*i0+2], nz);
    atomicAdd(&nacc[3*i1+0], nx); atomicAdd(&nacc[3*i1+1], ny); atomicAdd(&nacc[3*i1+2], nz);
    atomicAdd(&nacc[3*i2+0], nx); atomicAdd(&nacc[3*i2+1], ny); atomicAdd(&nacc[3*i2+2], nz);
    atomicAdd(&tacc[3*i0+0], tx); atomicAdd(&tacc[3*i0+1], ty); atomicAdd(&tacc[3*i0+2], tz);
    atomicAdd(&tacc[3*i1+0], tx); atomicAdd(&tacc[3*i1+1], ty); atomicAdd(&tacc[3*i1+2], tz);
    atomicAdd(&tacc[3*i2+0], tx); atomicAdd(&tacc[3*i2+1], ty); atomicAdd(&tacc[3*i2+2], tz);
}

__global__ void vg_finalize_kernel(float* __restrict__ nacc,
                                   float* __restrict__ tacc,
                                   int V) {
    int v = blockIdx.x * blockDim.x + threadIdx.x;
    if (v >= V) return;

    float nx = nacc[3*v+0], ny = nacc[3*v+1], nz = nacc[3*v+2];
    float nd = nx*nx + ny*ny + nz*nz;
    if (nd > EPS_LEN) {
        const float invn = 1.0f / sqrtf(nd);
        nx *= invn; ny *= invn; nz *= invn;
    } else {
        nx = 0.0f; ny = 0.0f; nz = 1.0f;
    }

    float tx = tacc[3*v+0], ty = tacc[3*v+1], tz = tacc[3*v+2];
    float td = tx*tx + ty*ty + tz*tz;
    float invt = 1.0f / sqrtf(fmaxf(td, EPS_LEN));
    tx *= invt; ty *= invt; tz *= invt;
    const float dp = tx*nx + ty*ny + tz*nz;
    tx -= dp*nx; ty -= dp*ny; tz -= dp*nz;
    float td2 = tx*tx + ty*ty + tz*tz;
    float invt2 = 1.0f / sqrtf(fmaxf(td2, EPS_LEN));
    tx *= invt2; ty *= invt2; tz *= invt2;

    nacc[3*v+0] = nx; nacc[3*v+1] = ny; nacc[3*v+2] = nz;
    tacc[3*v+0] = tx; tacc[3*v+1] = ty; tacc[3*v+2] = tz;
}

extern "C" void kernel_launch(void* const* d_in, const int* in_sizes, int n_in,
                              void* d_out, int out_size, void* d_ws, size_t ws_size,
                              hipStream_t stream) {
    const float* pos   = (const float*)d_in[0];
    const int*   faces = (const int*)  d_in[1];
    const float* tex   = (const float*)d_in[2];
    const int*   uvf   = (const int*)  d_in[3];

    const int V = in_sizes[0] / 3;
    const int F = in_sizes[1] / 3;

    float* out  = (float*)d_out;
    float* nacc = out;
    float* tacc = out + (size_t)3 * V;

    hipMemsetAsync(d_out, 0, (size_t)out_size * sizeof(float), stream);

    // ---- tier 1: fine buckets + packed u32 entries + 32B records ----
    const int NBC1 = (V + CBF - 1) >> CBF_LOG;
    {
        const size_t face_b = ((size_t)F * 8 * sizeof(float) + 255) & ~(size_t)255;
        const size_t E_b    = ((size_t)NBC1 * CAPF * sizeof(unsigned) + 255) & ~(size_t)255;
        const size_t cur_b  = ((size_t)(NBC1 + 1) * sizeof(int) + 255) & ~(size_t)255;
        const size_t need1  = face_b + E_b + 2 * cur_b + 256;

        if (ws_size >= need1 && NBC1 <= NBCP && F <= (1 << 22)) {
            char* ws = (char*)d_ws;
            float4*   fd4     = (float4*)ws;     ws += face_b;
            unsigned* E       = (unsigned*)ws;   ws += E_b;
            int*      cursors = (int*)ws;        ws += cur_b;
            int*      validw  = (int*)ws;
            int*      ovfp    = validw + NBC1;   // within cur_b padding

            hipMemsetAsync(cursors, 0, 2 * cur_b, stream);

            vg_face_bin_f8<<<(F + BLKA - 1) / BLKA, BLKA, 0, stream>>>(
                pos, faces, tex, uvf, fd4, E, cursors, validw, ovfp,
                nacc, tacc, F, NBC1);
            vg_gather_reduce_f8<<<NBC1, 512, 0, stream>>>(
                fd4, E, validw, ovfp, nacc, tacc, V);
            return;
        }
    }

    // ---- tier 2: round-3 proven path ----
    const int NBC2 = (V + CB2 - 1) >> CB2_LOG;
    {
        const size_t NE2    = (size_t)NBC2 * CAP2;
        const size_t face_b = ((size_t)F * FST2 * sizeof(float) + 255) & ~(size_t)255;
        const size_t ef_b   = (NE2 * 4 + 255) & ~(size_t)255;
        const size_t ev2_b  = (NE2 * 2 + 255) & ~(size_t)255;
        const size_t cur_b  = ((size_t)NBC2 * sizeof(int) + 255) & ~(size_t)255;
        const size_t need2  = face_b + ef_b + ev2_b + 2 * cur_b + 256;

        if (ws_size >= need2 && NBC2 <= 255 && F < (1 << 22)) {
            char* ws = (char*)d_ws;
            float*          face_data = (float*)ws;          ws += face_b;
            unsigned*       ef        = (unsigned*)ws;       ws += ef_b;
            unsigned short* ev        = (unsigned short*)ws; ws += ev2_b;
            int*            cursors   = (int*)ws;            ws += cur_b;
            int*            validw    = (int*)ws;

            hipMemsetAsync(cursors, 0, cur_b, stream);
            hipMemsetAsync(validw,  0, cur_b, stream);

            vg_face_bin3<<<(F + BLKA - 1) / BLKA, BLKA, 0, stream>>>(
                pos, faces, tex, uvf, face_data, ef, ev, cursors, validw,
                nacc, tacc, F, NBC2);
            vg_bucket_reduce3<<<NBC2, BLKA, 0, stream>>>(
                face_data, ef, ev, validw, nacc, tacc, V);
            return;
        }
    }

    // ---- tier 3: global atomics ----
    const int BLK = 256;
    vg_face_kernel<<<(F + BLK - 1) / BLK, BLK, 0, stream>>>(pos, faces, tex, uvf,
                                                            nacc, tacc, F);
    vg_finalize_kernel<<<(V + BLK - 1) / BLK, BLK, 0, stream>>>(nacc, tacc, V);
}